// Round 1
// baseline (3619.434 us; speedup 1.0000x reference)
//
#include <hip/hip_runtime.h>

#define S     512
#define NOBS  1024
#define NB    64
#define TT    512
#define CH    16     // chains per workgroup
#define NWAVE 8
#define NJT   4      // j-tiles (of 16 cols) per wave: 8 waves * 4 = 32 tiles = 512 cols
#define NGRP  4      // workgroups

typedef __attribute__((ext_vector_type(8))) short short8;
typedef __attribute__((ext_vector_type(4))) float f32x4;

__device__ __forceinline__ unsigned short f2bf(float x) {
  unsigned u = __builtin_bit_cast(unsigned, x);
  return (unsigned short)((u + 0x7fffu + ((u >> 16) & 1u)) >> 16);  // RNE
}

__device__ __forceinline__ float wave_max(float v) {
  for (int d = 32; d; d >>= 1) v = fmaxf(v, __shfl_xor(v, d));
  return v;
}
__device__ __forceinline__ float wave_sum(float v) {
  for (int d = 32; d; d >>= 1) v += __shfl_xor(v, d);
  return v;
}

// ---- log_pi log-softmax: lpi[j] = log_pi[j] - lse ----
__global__ void prep_pi(const float* __restrict__ log_pi, float* __restrict__ lpi) {
  const int l = threadIdx.x;
  float v[8];
  float mx = -INFINITY;
  for (int k = 0; k < 8; ++k) { v[k] = log_pi[l + 64 * k]; mx = fmaxf(mx, v[k]); }
  mx = wave_max(mx);
  float sm = 0.f;
  for (int k = 0; k < 8; ++k) sm += __expf(v[k] - mx);
  sm = wave_sum(sm);
  const float lse = mx + __logf(sm);
  for (int k = 0; k < 8; ++k) lpi[l + 64 * k] = v[k] - lse;
}

// ---- log_B row log-softmax, store LINEAR transposed: Bexp[o*S + j] = exp(lB[j][o]) ----
__global__ void prep_B(const float* __restrict__ log_B, float* __restrict__ Bexp) {
  const int j = blockIdx.x, l = threadIdx.x;
  const float* row = log_B + (size_t)j * NOBS;
  float v[16];
  float mx = -INFINITY;
  for (int k = 0; k < 16; ++k) { v[k] = row[l + 64 * k]; mx = fmaxf(mx, v[k]); }
  mx = wave_max(mx);
  float sm = 0.f;
  for (int k = 0; k < 16; ++k) sm += __expf(v[k] - mx);
  sm = wave_sum(sm);
  const float lse = mx + __logf(sm);
  for (int k = 0; k < 16; ++k) Bexp[(size_t)(l + 64 * k) * S + j] = __expf(v[k] - lse);
}

// ---- log_A row log-softmax, store exp() as bf16 in MFMA B-fragment order ----
// Block (jt,kk) holds Aexp[i=kk*32+g4*8+e][j=jt*16+jc] at ((jt*16+kk)*64 + g4*16+jc)*8 + e
__global__ void prep_A(const float* __restrict__ log_A, unsigned short* __restrict__ Afrag) {
  const int i = blockIdx.x, l = threadIdx.x;
  const float* row = log_A + (size_t)i * S;
  float v[8];
  float mx = -INFINITY;
  for (int k = 0; k < 8; ++k) { v[k] = row[l + 64 * k]; mx = fmaxf(mx, v[k]); }
  mx = wave_max(mx);
  float sm = 0.f;
  for (int k = 0; k < 8; ++k) sm += __expf(v[k] - mx);
  sm = wave_sum(sm);
  const float lse = mx + __logf(sm);
  const int kk = i >> 5, g4 = (i >> 3) & 3, e = i & 7;
  for (int k = 0; k < 8; ++k) {
    const int j = l + 64 * k;
    const int jt = j >> 4, jc = j & 15;
    const int lane = g4 * 16 + jc;
    Afrag[((size_t)(jt * 16 + kk) * 64 + lane) * 8 + e] = f2bf(__expf(v[k] - lse));
  }
}

// ---- main: 4 WGs x 16 chains, scaled-linear forward recurrence with bf16 MFMA ----
__global__ __launch_bounds__(512)
void hmm_main(const int* __restrict__ obs, const float* __restrict__ lpi,
              const float* __restrict__ Bexp, const unsigned short* __restrict__ Afrag,
              float* __restrict__ parts)
{
  __shared__ __align__(16) unsigned char Pb[CH * S * 2];  // 16 KB swizzled bf16 P
  __shared__ int   obs_s[CH][TT];                          // 32 KB
  __shared__ float pred[NWAVE][CH];
  __shared__ float inv_s[CH];
  __shared__ float logscale[CH];
  __shared__ float chain_ll[CH];

  const int tid = threadIdx.x;
  const int w   = tid >> 6;
  const int l   = tid & 63;
  const int g4  = l >> 4;
  const int jc  = l & 15;
  const int grp = blockIdx.x;

  for (int m = 0; m < CH; ++m)
    obs_s[m][tid] = obs[(size_t)(grp * CH + m) * TT + tid];
  __syncthreads();

  for (int t = 0; t < TT; ++t) {
    f32x4 vals[NJT];
    const bool finalstep = (t == TT - 1);

    if (t == 0) {
      // alpha0 = lpi[j] + log B[j][o0]  (log space)
      for (int ji = 0; ji < NJT; ++ji) {
        const int jt = w + NWAVE * ji;
        const int j  = jt * 16 + jc;
        const float lp = lpi[j];
        for (int r = 0; r < 4; ++r) {
          const int o = obs_s[g4 * 4 + r][0];
          vals[ji][r] = lp + __logf(Bexp[(size_t)o * S + j]);
        }
      }
    } else {
      // A-operand fragments of P from LDS (shared across jt)
      short8 af[16];
      #pragma unroll
      for (int kk = 0; kk < 16; ++kk) {
        const unsigned a = (unsigned)(jc * 1024 + kk * 64 + g4 * 16) ^ ((unsigned)(jc & 7) << 4);
        af[kk] = *reinterpret_cast<const short8*>(&Pb[a]);
      }
      #pragma unroll
      for (int ji = 0; ji < NJT; ++ji) {
        const int jt = w + NWAVE * ji;
        const unsigned short* bp = Afrag + (size_t)(jt * 16) * 512 + l * 8;
        f32x4 acc = {0.f, 0.f, 0.f, 0.f};
        #pragma unroll
        for (int kk = 0; kk < 16; ++kk) {
          short8 bf = *reinterpret_cast<const short8*>(bp + (size_t)kk * 512);
          acc = __builtin_amdgcn_mfma_f32_16x16x32_bf16(af[kk], bf, acc, 0, 0, 0);
        }
        const int j = jt * 16 + jc;
        #pragma unroll
        for (int r = 0; r < 4; ++r) {
          const int o = obs_s[g4 * 4 + r][t];
          acc[r] *= Bexp[(size_t)o * S + j];  // emission (linear)
        }
        vals[ji] = acc;
      }
    }

    // per-chain reduction: max (normalization) or sum (final step)
    #pragma unroll
    for (int r = 0; r < 4; ++r) {
      float v;
      if (finalstep) {
        v = vals[0][r] + vals[1][r] + vals[2][r] + vals[3][r];
        for (int d = 1; d < 16; d <<= 1) v += __shfl_xor(v, d);
      } else {
        v = fmaxf(fmaxf(vals[0][r], vals[1][r]), fmaxf(vals[2][r], vals[3][r]));
        for (int d = 1; d < 16; d <<= 1) v = fmaxf(v, __shfl_xor(v, d));
      }
      if (jc == 0) pred[w][g4 * 4 + r] = v;
    }
    __syncthreads();

    if (tid < CH) {
      const int m = tid;
      if (finalstep) {
        float s = 0.f;
        for (int ww = 0; ww < NWAVE; ++ww) s += pred[ww][m];
        chain_ll[m] = logscale[m] + __logf(s);
      } else {
        float s = pred[0][m];
        for (int ww = 1; ww < NWAVE; ++ww) s = fmaxf(s, pred[ww][m]);
        if (t == 0) { logscale[m] = s;            inv_s[m] = s; }
        else        { logscale[m] += __logf(s);   inv_s[m] = 1.0f / s; }
      }
    }
    __syncthreads();

    if (!finalstep) {
      // write normalized P (bf16, swizzled) for next step
      #pragma unroll
      for (int ji = 0; ji < NJT; ++ji) {
        const int jt = w + NWAVE * ji;
        const int j  = jt * 16 + jc;
        #pragma unroll
        for (int r = 0; r < 4; ++r) {
          const int m = g4 * 4 + r;
          const float p = (t == 0) ? __expf(vals[ji][r] - inv_s[m])
                                   : vals[ji][r] * inv_s[m];
          const unsigned a = (unsigned)(m * 1024 + j * 2) ^ ((unsigned)(m & 7) << 4);
          *reinterpret_cast<unsigned short*>(&Pb[a]) = f2bf(p);
        }
      }
      __syncthreads();
    }
  }

  if (tid == 0) {
    float ssum = 0.f;
    for (int m = 0; m < CH; ++m) ssum += chain_ll[m];
    parts[grp] = ssum;
  }
}

__global__ void final_sum(const float* __restrict__ parts, float* __restrict__ out) {
  out[0] = parts[0] + parts[1] + parts[2] + parts[3];
}

extern "C" void kernel_launch(void* const* d_in, const int* in_sizes, int n_in,
                              void* d_out, int out_size, void* d_ws, size_t ws_size,
                              hipStream_t stream) {
  const int*   obs  = (const int*)d_in[0];
  const float* lgpi = (const float*)d_in[1];
  const float* lgA  = (const float*)d_in[2];
  const float* lgB  = (const float*)d_in[3];
  float* out = (float*)d_out;

  char* ws = (char*)d_ws;
  float*          Bexp  = (float*)ws;                                        // 2 MB
  unsigned short* Afrag = (unsigned short*)(ws + (size_t)NOBS * S * 4);      // 512 KB
  float*          lpi   = (float*)(ws + (size_t)NOBS * S * 4 + (size_t)S * S * 2);
  float*          parts = lpi + S;

  prep_pi<<<1, 64, 0, stream>>>(lgpi, lpi);
  prep_B<<<S, 64, 0, stream>>>(lgB, Bexp);
  prep_A<<<S, 64, 0, stream>>>(lgA, Afrag);
  hmm_main<<<NGRP, 512, 0, stream>>>(obs, lpi, Bexp, Afrag, parts);
  final_sum<<<1, 1, 0, stream>>>(parts, out);
}

// Round 2
// 1257.814 us; speedup vs baseline: 2.8776x; 2.8776x over previous
//
#include <hip/hip_runtime.h>

#define S     512
#define NOBS  1024
#define TT    512
#define CH    16     // chains per workgroup (= MFMA M)
#define NWAVE 8
#define NJT   4      // j-tiles (16 cols) per wave: 8*4 = 32 tiles = 512 cols
#define NGRP  4

typedef __attribute__((ext_vector_type(4))) float f32x4;
typedef long i64;

__device__ __forceinline__ unsigned short f2bf(float x) {
  unsigned u = __builtin_bit_cast(unsigned, x);
  return (unsigned short)((u + 0x7fffu + ((u >> 16) & 1u)) >> 16);  // RNE
}
__device__ __forceinline__ float bf2f(unsigned short u) {
  unsigned x = ((unsigned)u) << 16;
  return __builtin_bit_cast(float, x);
}

__device__ __forceinline__ unsigned char f2fp8(float x) {
#if __has_builtin(__builtin_amdgcn_cvt_pk_fp8_f32)
  int r = __builtin_amdgcn_cvt_pk_fp8_f32(x, x, 0, false);
  return (unsigned char)(r & 0xff);
#else
  // software e4m3fn (x >= 0), RNE
  x = fminf(fmaxf(x, 0.f), 448.f);
  unsigned u = __builtin_bit_cast(unsigned, x);
  int ex = (int)((u >> 23) & 0xff);
  if (ex >= 121) {  // >= 2^-6, normal range
    unsigned m = (u & 0x7fffff) | 0x800000;
    unsigned keep = m >> 20, rest = m & 0xfffff;
    keep += (rest > 0x80000u) || (rest == 0x80000u && (keep & 1));
    int e8 = ex - 127 + 7;
    if (keep == 16) { keep = 8; e8++; }
    if (e8 >= 16) return 0x7e;
    return (unsigned char)((e8 << 3) | (keep & 7));
  } else {
    int m = (int)(x * 512.0f + 0.5f);
    if (m > 8) m = 8;
    return (unsigned char)m;   // m==8 encodes 2^-6 exactly
  }
#endif
}

__device__ __forceinline__ float wave_max(float v) {
  for (int d = 32; d; d >>= 1) v = fmaxf(v, __shfl_xor(v, d));
  return v;
}
__device__ __forceinline__ float wave_sum(float v) {
  for (int d = 32; d; d >>= 1) v += __shfl_xor(v, d);
  return v;
}

// ---- log_pi log-softmax ----
__global__ void prep_pi(const float* __restrict__ log_pi, float* __restrict__ lpi) {
  const int l = threadIdx.x;
  float v[8];
  float mx = -INFINITY;
  for (int k = 0; k < 8; ++k) { v[k] = log_pi[l + 64 * k]; mx = fmaxf(mx, v[k]); }
  mx = wave_max(mx);
  float sm = 0.f;
  for (int k = 0; k < 8; ++k) sm += __expf(v[k] - mx);
  sm = wave_sum(sm);
  const float lse = mx + __logf(sm);
  for (int k = 0; k < 8; ++k) lpi[l + 64 * k] = v[k] - lse;
}

// ---- log_B row log-softmax -> bf16 transposed: Bexp16[o*S + j] = exp(lB[j][o]) ----
__global__ void prep_B(const float* __restrict__ log_B, unsigned short* __restrict__ Bexp16) {
  const int j = blockIdx.x, l = threadIdx.x;
  const float* row = log_B + (size_t)j * NOBS;
  float v[16];
  float mx = -INFINITY;
  for (int k = 0; k < 16; ++k) { v[k] = row[l + 64 * k]; mx = fmaxf(mx, v[k]); }
  mx = wave_max(mx);
  float sm = 0.f;
  for (int k = 0; k < 16; ++k) sm += __expf(v[k] - mx);
  sm = wave_sum(sm);
  const float lse = mx + __logf(sm);
  for (int k = 0; k < 16; ++k) Bexp16[(size_t)(l + 64 * k) * S + j] = f2bf(__expf(v[k] - lse));
}

// ---- log_A row log-softmax -> fp8 e4m3 in MFMA B-fragment order ----
// byte index = ((jt*16 + kk)*64 + lane)*8 + e, lane = g4*16 + jc,
// holds Aexp[i = kk*32 + g4*8 + e][j = jt*16 + jc]
__global__ void prep_A(const float* __restrict__ log_A, unsigned char* __restrict__ Afrag8) {
  const int i = blockIdx.x, l = threadIdx.x;
  const float* row = log_A + (size_t)i * S;
  float v[8];
  float mx = -INFINITY;
  for (int k = 0; k < 8; ++k) { v[k] = row[l + 64 * k]; mx = fmaxf(mx, v[k]); }
  mx = wave_max(mx);
  float sm = 0.f;
  for (int k = 0; k < 8; ++k) sm += __expf(v[k] - mx);
  sm = wave_sum(sm);
  const float lse = mx + __logf(sm);
  const int kk = i >> 5, g4 = (i >> 3) & 3, e = i & 7;
  for (int k = 0; k < 8; ++k) {
    const int j = l + 64 * k;
    const int jt = j >> 4, jc = j & 15;
    const int lane = g4 * 16 + jc;
    Afrag8[((size_t)(jt * 16 + kk) * 64 + lane) * 8 + e] = f2fp8(__expf(v[k] - lse));
  }
}

// ---- main: A held entirely in VGPRs (fp8), P in swizzled LDS (fp8) ----
__global__ __launch_bounds__(512, 2)
void hmm_main(const int* __restrict__ obs, const float* __restrict__ lpi,
              const unsigned short* __restrict__ Bexp16,
              const i64* __restrict__ Afrag8, float* __restrict__ parts)
{
  __shared__ __align__(16) unsigned char Pb[CH * S];   // 8 KB fp8, XOR-swizzled
  __shared__ int   obs_s[CH][TT];                      // 32 KB
  __shared__ float pred[NWAVE][CH];
  __shared__ float inv_s[CH];
  __shared__ float logscale[CH];
  __shared__ float chain_ll[CH];

  const int tid = threadIdx.x;
  const int w   = tid >> 6;
  const int l   = tid & 63;
  const int g4  = l >> 4;
  const int jc  = l & 15;
  const int grp = blockIdx.x;

  // persistent A fragments: 4 tiles x 16 kk x 2 VGPR = 128 VGPRs
  i64 a_frags[NJT][16];
  #pragma unroll
  for (int ji = 0; ji < NJT; ++ji) {
    const int jt = w + NWAVE * ji;
    #pragma unroll
    for (int kk = 0; kk < 16; ++kk)
      a_frags[ji][kk] = Afrag8[(size_t)(jt * 16 + kk) * 64 + l];
  }

  for (int m = 0; m < CH; ++m)
    obs_s[m][tid] = obs[(size_t)(grp * CH + m) * TT + tid];
  __syncthreads();

  for (int t = 0; t < TT; ++t) {
    const bool finalstep = (t == TT - 1);
    int ob[4];
    #pragma unroll
    for (int r = 0; r < 4; ++r) ob[r] = obs_s[g4 * 4 + r][t];

    f32x4 vals[NJT];

    if (t == 0) {
      #pragma unroll
      for (int ji = 0; ji < NJT; ++ji) {
        const int j = (w + NWAVE * ji) * 16 + jc;
        const float lp = lpi[j];
        #pragma unroll
        for (int r = 0; r < 4; ++r)
          vals[ji][r] = lp + __logf(bf2f(Bexp16[(size_t)ob[r] * S + j]));
      }
    } else {
      // emission prefetch (independent of MFMA chain -> overlaps)
      unsigned short eb[NJT][4];
      #pragma unroll
      for (int ji = 0; ji < NJT; ++ji) {
        const int j = (w + NWAVE * ji) * 16 + jc;
        #pragma unroll
        for (int r = 0; r < 4; ++r) eb[ji][r] = Bexp16[(size_t)ob[r] * S + j];
      }
      // P fragments (A-operand): chain row = l&15, k = (l>>4)*8 + e
      i64 af[16];
      #pragma unroll
      for (int kk = 0; kk < 16; ++kk) {
        const int slot = kk * 4 + g4;                 // (kk*32 + g4*8) >> 3
        af[kk] = *reinterpret_cast<const i64*>(&Pb[jc * S + (((slot ^ jc) & 63) << 3)]);
      }
      #pragma unroll
      for (int ji = 0; ji < NJT; ++ji) {
        f32x4 acc = {0.f, 0.f, 0.f, 0.f};
        #pragma unroll
        for (int kk = 0; kk < 16; ++kk)
          acc = __builtin_amdgcn_mfma_f32_16x16x32_fp8_fp8(af[kk], a_frags[ji][kk], acc, 0, 0, 0);
        #pragma unroll
        for (int r = 0; r < 4; ++r) acc[r] *= bf2f(eb[ji][r]);
        vals[ji] = acc;
      }
    }

    // per-chain reduction over j: max (normalize) or sum (final)
    #pragma unroll
    for (int r = 0; r < 4; ++r) {
      float v;
      if (finalstep) {
        v = vals[0][r] + vals[1][r] + vals[2][r] + vals[3][r];
        for (int d = 1; d < 16; d <<= 1) v += __shfl_xor(v, d);
      } else {
        v = fmaxf(fmaxf(vals[0][r], vals[1][r]), fmaxf(vals[2][r], vals[3][r]));
        for (int d = 1; d < 16; d <<= 1) v = fmaxf(v, __shfl_xor(v, d));
      }
      if (jc == 0) pred[w][g4 * 4 + r] = v;
    }
    __syncthreads();

    if (tid < CH) {
      const int m = tid;
      if (finalstep) {
        float s = 0.f;
        for (int ww = 0; ww < NWAVE; ++ww) s += pred[ww][m];
        chain_ll[m] = logscale[m] + __logf(s);
      } else {
        float s = pred[0][m];
        for (int ww = 1; ww < NWAVE; ++ww) s = fmaxf(s, pred[ww][m]);
        if (t == 0) { logscale[m] = s;          inv_s[m] = s; }
        else        { logscale[m] += __logf(s); inv_s[m] = 1.0f / s; }
      }
    }
    __syncthreads();

    if (!finalstep) {
      #pragma unroll
      for (int ji = 0; ji < NJT; ++ji) {
        const int j = (w + NWAVE * ji) * 16 + jc;
        #pragma unroll
        for (int r = 0; r < 4; ++r) {
          const int m = g4 * 4 + r;
          const float p = (t == 0) ? __expf(vals[ji][r] - inv_s[m])
                                   : vals[ji][r] * inv_s[m];
          Pb[m * S + ((((j >> 3) ^ m) & 63) << 3) + (j & 7)] = f2fp8(p);
        }
      }
      __syncthreads();
    }
  }

  if (tid == 0) {
    float ssum = 0.f;
    for (int m = 0; m < CH; ++m) ssum += chain_ll[m];
    parts[grp] = ssum;
  }
}

__global__ void final_sum(const float* __restrict__ parts, float* __restrict__ out) {
  out[0] = parts[0] + parts[1] + parts[2] + parts[3];
}

extern "C" void kernel_launch(void* const* d_in, const int* in_sizes, int n_in,
                              void* d_out, int out_size, void* d_ws, size_t ws_size,
                              hipStream_t stream) {
  const int*   obs  = (const int*)d_in[0];
  const float* lgpi = (const float*)d_in[1];
  const float* lgA  = (const float*)d_in[2];
  const float* lgB  = (const float*)d_in[3];
  float* out = (float*)d_out;

  char* ws = (char*)d_ws;
  unsigned short* Bexp16 = (unsigned short*)ws;                       // 1 MB
  unsigned char*  Afrag8 = (unsigned char*)(ws + (size_t)NOBS * S * 2); // 256 KB
  float*          lpi    = (float*)(ws + (size_t)NOBS * S * 2 + (size_t)S * S);
  float*          parts  = lpi + S;

  prep_pi<<<1, 64, 0, stream>>>(lgpi, lpi);
  prep_B<<<S, 64, 0, stream>>>(lgB, Bexp16);
  prep_A<<<S, 64, 0, stream>>>(lgA, Afrag8);
  hmm_main<<<NGRP, 512, 0, stream>>>(obs, lpi, Bexp16, (const i64*)Afrag8, parts);
  final_sum<<<1, 1, 0, stream>>>(parts, out);
}

// Round 3
// 1164.381 us; speedup vs baseline: 3.1085x; 1.0802x over previous
//
#include <hip/hip_runtime.h>

#define S     512
#define NOBS  1024
#define TT    512
#define CH    16     // chains per workgroup (= MFMA M)
#define NWAVE 8
#define NJT   4      // j-tiles (16 cols) per wave: 8*4 = 32 tiles = 512 cols
#define NGRP  4

typedef __attribute__((ext_vector_type(4))) float f32x4;
typedef __attribute__((ext_vector_type(4))) int   i32x4;
typedef __attribute__((ext_vector_type(8))) int   i32x8;
typedef long i64;

__device__ __forceinline__ unsigned short f2bf(float x) {
  unsigned u = __builtin_bit_cast(unsigned, x);
  return (unsigned short)((u + 0x7fffu + ((u >> 16) & 1u)) >> 16);  // RNE
}
__device__ __forceinline__ float bf2f(unsigned short u) {
  unsigned x = ((unsigned)u) << 16;
  return __builtin_bit_cast(float, x);
}

__device__ __forceinline__ unsigned char f2fp8(float x) {
#if __has_builtin(__builtin_amdgcn_cvt_pk_fp8_f32)
  int r = __builtin_amdgcn_cvt_pk_fp8_f32(x, x, 0, false);
  return (unsigned char)(r & 0xff);
#else
  x = fminf(fmaxf(x, 0.f), 448.f);
  unsigned u = __builtin_bit_cast(unsigned, x);
  int ex = (int)((u >> 23) & 0xff);
  if (ex >= 121) {
    unsigned m = (u & 0x7fffff) | 0x800000;
    unsigned keep = m >> 20, rest = m & 0xfffff;
    keep += (rest > 0x80000u) || (rest == 0x80000u && (keep & 1));
    int e8 = ex - 127 + 7;
    if (keep == 16) { keep = 8; e8++; }
    if (e8 >= 16) return 0x7e;
    return (unsigned char)((e8 << 3) | (keep & 7));
  } else {
    int m = (int)(x * 512.0f + 0.5f);
    if (m > 8) m = 8;
    return (unsigned char)m;
  }
#endif
}

__device__ __forceinline__ float wave_max(float v) {
  for (int d = 32; d; d >>= 1) v = fmaxf(v, __shfl_xor(v, d));
  return v;
}
__device__ __forceinline__ float wave_sum(float v) {
  for (int d = 32; d; d >>= 1) v += __shfl_xor(v, d);
  return v;
}

// ---- log_pi log-softmax ----
__global__ void prep_pi(const float* __restrict__ log_pi, float* __restrict__ lpi) {
  const int l = threadIdx.x;
  float v[8];
  float mx = -INFINITY;
  for (int k = 0; k < 8; ++k) { v[k] = log_pi[l + 64 * k]; mx = fmaxf(mx, v[k]); }
  mx = wave_max(mx);
  float sm = 0.f;
  for (int k = 0; k < 8; ++k) sm += __expf(v[k] - mx);
  sm = wave_sum(sm);
  const float lse = mx + __logf(sm);
  for (int k = 0; k < 8; ++k) lpi[l + 64 * k] = v[k] - lse;
}

// ---- log_B row log-softmax -> bf16 transposed: Bexp16[o*S + j] = exp(lB[j][o]) ----
__global__ void prep_B(const float* __restrict__ log_B, unsigned short* __restrict__ Bexp16) {
  const int j = blockIdx.x, l = threadIdx.x;
  const float* row = log_B + (size_t)j * NOBS;
  float v[16];
  float mx = -INFINITY;
  for (int k = 0; k < 16; ++k) { v[k] = row[l + 64 * k]; mx = fmaxf(mx, v[k]); }
  mx = wave_max(mx);
  float sm = 0.f;
  for (int k = 0; k < 16; ++k) sm += __expf(v[k] - mx);
  sm = wave_sum(sm);
  const float lse = mx + __logf(sm);
  for (int k = 0; k < 16; ++k) Bexp16[(size_t)(l + 64 * k) * S + j] = f2bf(__expf(v[k] - lse));
}

// ---- log_A row log-softmax -> fp8 e4m3, K=128-chunk fragment order ----
// Afrag8[ ((jt*4 + c)*64 + g4*16 + jc)*32 + e ] = Aexp[i = c*128 + g4*32 + e][j = jt*16 + jc]
__global__ void prep_A(const float* __restrict__ log_A, unsigned char* __restrict__ Afrag8) {
  const int i = blockIdx.x, l = threadIdx.x;
  const float* row = log_A + (size_t)i * S;
  float v[8];
  float mx = -INFINITY;
  for (int k = 0; k < 8; ++k) { v[k] = row[l + 64 * k]; mx = fmaxf(mx, v[k]); }
  mx = wave_max(mx);
  float sm = 0.f;
  for (int k = 0; k < 8; ++k) sm += __expf(v[k] - mx);
  sm = wave_sum(sm);
  const float lse = mx + __logf(sm);
  const int c = i >> 7, g4s = (i >> 5) & 3, e = i & 31;
  for (int k = 0; k < 8; ++k) {
    const int j = l + 64 * k;
    const int jt = j >> 4, jc = j & 15;
    Afrag8[((size_t)(jt * 4 + c) * 64 + g4s * 16 + jc) * 32 + e] = f2fp8(__expf(v[k] - lse));
  }
}

// P LDS swizzle: byte for (row m, k) at  m*512 + (((k>>4) ^ m)&31)*16 + (k&15)
__device__ __forceinline__ int pswz(int m, int g) { return m * 512 + (((g ^ m) & 31) << 4); }

// ---- main: A in VGPRs (fp8, K=128 chunks), P in 16B-XOR-swizzled LDS (fp8) ----
__global__ __launch_bounds__(512, 2)
void hmm_main(const int* __restrict__ obs, const float* __restrict__ lpi,
              const unsigned short* __restrict__ Bexp16,
              const unsigned char* __restrict__ Afrag8, float* __restrict__ parts)
{
  __shared__ __align__(16) unsigned char Pb[CH * S];   // 8 KB fp8
  __shared__ int   obs_s[CH][TT];                      // 32 KB
  __shared__ __align__(16) float pred[CH][NWAVE];      // per-wave partials
  __shared__ float chain_ll[CH];

  const int tid = threadIdx.x;
  const int w   = tid >> 6;
  const int l   = tid & 63;
  const int g4  = l >> 4;
  const int jc  = l & 15;
  const int grp = blockIdx.x;

  // persistent A fragments: 4 tiles x 4 chunks x 8 VGPR = 128 VGPRs
  i32x8 a_frags[NJT][4];
  #pragma unroll
  for (int ji = 0; ji < NJT; ++ji) {
    const int jt = w + NWAVE * ji;
    #pragma unroll
    for (int c = 0; c < 4; ++c)
      a_frags[ji][c] = *reinterpret_cast<const i32x8*>(
          Afrag8 + ((size_t)(jt * 4 + c) * 64 + l) * 32);
  }

  for (int m = 0; m < CH; ++m)
    obs_s[m][tid] = obs[(size_t)(grp * CH + m) * TT + tid];
  __syncthreads();

  float lsc[4];   // running log-scale for chains m = g4*4 + r (replicated)

  for (int t = 0; t < TT; ++t) {
    const bool fin = (t == TT - 1);
    int ob[4];
    #pragma unroll
    for (int r = 0; r < 4; ++r) ob[r] = obs_s[g4 * 4 + r][t];

    f32x4 vals[NJT];

    if (t == 0) {
      #pragma unroll
      for (int ji = 0; ji < NJT; ++ji) {
        const int j = (w + NWAVE * ji) * 16 + jc;
        const float lp = lpi[j];
        #pragma unroll
        for (int r = 0; r < 4; ++r)
          vals[ji][r] = lp + __logf(bf2f(Bexp16[(size_t)ob[r] * S + j]));
      }
    } else {
      // emission prefetch (global, overlaps with MFMA chain)
      unsigned short eb[NJT][4];
      #pragma unroll
      for (int r = 0; r < 4; ++r) {
        const unsigned short* bp = Bexp16 + (size_t)ob[r] * S + (w * 16 + jc);
        #pragma unroll
        for (int ji = 0; ji < NJT; ++ji) eb[ji][r] = bp[ji * NWAVE * 16];
      }
      // P fragments (A-operand): row = jc, k = c*128 + g4*32 + e
      i32x8 af[4];
      #pragma unroll
      for (int c = 0; c < 4; ++c) {
        const int g0 = c * 8 + g4 * 2;
        i32x4 lo = *reinterpret_cast<const i32x4*>(&Pb[pswz(jc, g0)]);
        i32x4 hi = *reinterpret_cast<const i32x4*>(&Pb[pswz(jc, g0 + 1)]);
        af[c] = i32x8{lo[0], lo[1], lo[2], lo[3], hi[0], hi[1], hi[2], hi[3]};
      }
      #pragma unroll
      for (int ji = 0; ji < NJT; ++ji) {
        f32x4 acc = {0.f, 0.f, 0.f, 0.f};
        #pragma unroll
        for (int c = 0; c < 4; ++c) {
#if __has_builtin(__builtin_amdgcn_mfma_scale_f32_16x16x128_f8f6f4)
          acc = __builtin_amdgcn_mfma_scale_f32_16x16x128_f8f6f4(
                    af[c], a_frags[ji][c], acc, 0, 0,
                    0, 0x7f7f7f7f, 0, 0x7f7f7f7f);
#else
          const i64* pa = reinterpret_cast<const i64*>(&af[c]);
          const i64* pb = reinterpret_cast<const i64*>(&a_frags[ji][c]);
          #pragma unroll
          for (int q = 0; q < 4; ++q)
            acc = __builtin_amdgcn_mfma_f32_16x16x32_fp8_fp8(pa[q], pb[q], acc, 0, 0, 0);
#endif
        }
        #pragma unroll
        for (int r = 0; r < 4; ++r) acc[r] *= bf2f(eb[ji][r]);
        vals[ji] = acc;
      }
    }

    // per-(wave,chain) partial over the wave's 64 cols: max (or sum on final)
    #pragma unroll
    for (int r = 0; r < 4; ++r) {
      float v;
      if (fin) {
        v = vals[0][r] + vals[1][r] + vals[2][r] + vals[3][r];
        for (int d = 1; d < 16; d <<= 1) v += __shfl_xor(v, d);
      } else {
        v = fmaxf(fmaxf(vals[0][r], vals[1][r]), fmaxf(vals[2][r], vals[3][r]));
        for (int d = 1; d < 16; d <<= 1) v = fmaxf(v, __shfl_xor(v, d));
      }
      if (jc == 0) pred[g4 * 4 + r][w] = v;
    }
    __syncthreads();

    if (!fin) {
      // distributed finalize: every thread handles its 4 chains
      float inv4[4];
      #pragma unroll
      for (int r = 0; r < 4; ++r) {
        const int m = g4 * 4 + r;
        const f32x4 p0 = *reinterpret_cast<const f32x4*>(&pred[m][0]);
        const f32x4 p1 = *reinterpret_cast<const f32x4*>(&pred[m][4]);
        float s = fmaxf(fmaxf(fmaxf(p0[0], p0[1]), fmaxf(p0[2], p0[3])),
                        fmaxf(fmaxf(p1[0], p1[1]), fmaxf(p1[2], p1[3])));
        if (t == 0) { lsc[r] = s;            inv4[r] = s; }
        else        { lsc[r] += __logf(s);   inv4[r] = __builtin_amdgcn_rcpf(s); }
      }
      // normalized P write (fp8, swizzled)
      #pragma unroll
      for (int ji = 0; ji < NJT; ++ji) {
        const int jt = w + NWAVE * ji;
        #pragma unroll
        for (int r = 0; r < 4; ++r) {
          const int m = g4 * 4 + r;
          const float p = (t == 0) ? __expf(vals[ji][r] - inv4[r])
                                   : vals[ji][r] * inv4[r];
          Pb[pswz(m, jt) + jc] = f2fp8(p);
        }
      }
      __syncthreads();
    } else {
      if (w == 0 && jc == 0) {
        #pragma unroll
        for (int r = 0; r < 4; ++r) {
          const int m = g4 * 4 + r;
          float s8 = 0.f;
          for (int ww = 0; ww < NWAVE; ++ww) s8 += pred[m][ww];
          chain_ll[m] = lsc[r] + __logf(s8);
        }
      }
      __syncthreads();
      if (tid == 0) {
        float ssum = 0.f;
        for (int m = 0; m < CH; ++m) ssum += chain_ll[m];
        parts[grp] = ssum;
      }
    }
  }
}

__global__ void final_sum(const float* __restrict__ parts, float* __restrict__ out) {
  out[0] = parts[0] + parts[1] + parts[2] + parts[3];
}

extern "C" void kernel_launch(void* const* d_in, const int* in_sizes, int n_in,
                              void* d_out, int out_size, void* d_ws, size_t ws_size,
                              hipStream_t stream) {
  const int*   obs  = (const int*)d_in[0];
  const float* lgpi = (const float*)d_in[1];
  const float* lgA  = (const float*)d_in[2];
  const float* lgB  = (const float*)d_in[3];
  float* out = (float*)d_out;

  char* ws = (char*)d_ws;
  unsigned short* Bexp16 = (unsigned short*)ws;                          // 1 MB
  unsigned char*  Afrag8 = (unsigned char*)(ws + (size_t)NOBS * S * 2);  // 256 KB
  float*          lpi    = (float*)(ws + (size_t)NOBS * S * 2 + (size_t)S * S);
  float*          parts  = lpi + S;

  prep_pi<<<1, 64, 0, stream>>>(lgpi, lpi);
  prep_B<<<S, 64, 0, stream>>>(lgB, Bexp16);
  prep_A<<<S, 64, 0, stream>>>(lgA, Afrag8);
  hmm_main<<<NGRP, 512, 0, stream>>>(obs, lpi, Bexp16, Afrag8, parts);
  final_sum<<<1, 1, 0, stream>>>(parts, out);
}

// Round 4
// 841.601 us; speedup vs baseline: 4.3007x; 1.3835x over previous
//
#include <hip/hip_runtime.h>

#define S     512
#define NOBS  1024
#define TT    512
#define CH    16     // chains per workgroup (= MFMA N after swap)
#define NWAVE 8
#define NJT   4      // j-tiles (16 rows) per wave: 8*4 = 32 tiles = 512 rows
#define NGRP  4

typedef __attribute__((ext_vector_type(4))) float f32x4;
typedef __attribute__((ext_vector_type(4))) int   i32x4;
typedef __attribute__((ext_vector_type(8))) int   i32x8;
typedef __attribute__((ext_vector_type(2))) unsigned int u32x2;
typedef long i64;

__device__ __forceinline__ unsigned short f2bf(float x) {
  unsigned u = __builtin_bit_cast(unsigned, x);
  return (unsigned short)((u + 0x7fffu + ((u >> 16) & 1u)) >> 16);  // RNE
}
__device__ __forceinline__ float bflo(unsigned u) {  // bf16 in low half -> f32
  return __builtin_bit_cast(float, u << 16);
}
__device__ __forceinline__ float bfhi(unsigned u) {  // bf16 in high half -> f32
  return __builtin_bit_cast(float, u & 0xffff0000u);
}

__device__ __forceinline__ unsigned char f2fp8_sw(float x) {
  x = fminf(fmaxf(x, 0.f), 448.f);
  unsigned u = __builtin_bit_cast(unsigned, x);
  int ex = (int)((u >> 23) & 0xff);
  if (ex >= 121) {
    unsigned m = (u & 0x7fffff) | 0x800000;
    unsigned keep = m >> 20, rest = m & 0xfffff;
    keep += (rest > 0x80000u) || (rest == 0x80000u && (keep & 1));
    int e8 = ex - 127 + 7;
    if (keep == 16) { keep = 8; e8++; }
    if (e8 >= 16) return 0x7e;
    return (unsigned char)((e8 << 3) | (keep & 7));
  } else {
    int m = (int)(x * 512.0f + 0.5f);
    if (m > 8) m = 8;
    return (unsigned char)m;
  }
}

__device__ __forceinline__ unsigned pack4_fp8(float p0, float p1, float p2, float p3) {
#if __has_builtin(__builtin_amdgcn_cvt_pk_fp8_f32)
  int v = __builtin_amdgcn_cvt_pk_fp8_f32(p0, p1, 0, false);   // bytes 0,1
  v = __builtin_amdgcn_cvt_pk_fp8_f32(p2, p3, v, true);        // bytes 2,3
  return (unsigned)v;
#else
  return (unsigned)f2fp8_sw(p0) | ((unsigned)f2fp8_sw(p1) << 8) |
         ((unsigned)f2fp8_sw(p2) << 16) | ((unsigned)f2fp8_sw(p3) << 24);
#endif
}

__device__ __forceinline__ float wave_max(float v) {
  for (int d = 32; d; d >>= 1) v = fmaxf(v, __shfl_xor(v, d));
  return v;
}
__device__ __forceinline__ float wave_sum(float v) {
  for (int d = 32; d; d >>= 1) v += __shfl_xor(v, d);
  return v;
}

// ---- log_pi log-softmax ----
__global__ void prep_pi(const float* __restrict__ log_pi, float* __restrict__ lpi) {
  const int l = threadIdx.x;
  float v[8];
  float mx = -INFINITY;
  for (int k = 0; k < 8; ++k) { v[k] = log_pi[l + 64 * k]; mx = fmaxf(mx, v[k]); }
  mx = wave_max(mx);
  float sm = 0.f;
  for (int k = 0; k < 8; ++k) sm += __expf(v[k] - mx);
  sm = wave_sum(sm);
  const float lse = mx + __logf(sm);
  for (int k = 0; k < 8; ++k) lpi[l + 64 * k] = v[k] - lse;
}

// ---- log_B row log-softmax -> bf16 transposed: Bexp16[o*S + j] = exp(lB[j][o]) ----
__global__ void prep_B(const float* __restrict__ log_B, unsigned short* __restrict__ Bexp16) {
  const int j = blockIdx.x, l = threadIdx.x;
  const float* row = log_B + (size_t)j * NOBS;
  float v[16];
  float mx = -INFINITY;
  for (int k = 0; k < 16; ++k) { v[k] = row[l + 64 * k]; mx = fmaxf(mx, v[k]); }
  mx = wave_max(mx);
  float sm = 0.f;
  for (int k = 0; k < 16; ++k) sm += __expf(v[k] - mx);
  sm = wave_sum(sm);
  const float lse = mx + __logf(sm);
  for (int k = 0; k < 16; ++k) Bexp16[(size_t)(l + 64 * k) * S + j] = f2bf(__expf(v[k] - lse));
}

// ---- log_A row log-softmax -> fp8 e4m3, K=128-chunk fragment order ----
// Afrag8[ ((jt*4 + c)*64 + lane)*32 + e ] = Aexp[i = c*128 + (lane>>4)*32 + e][j = jt*16 + (lane&15)]
__global__ void prep_A(const float* __restrict__ log_A, unsigned char* __restrict__ Afrag8) {
  const int i = blockIdx.x, l = threadIdx.x;
  const float* row = log_A + (size_t)i * S;
  float v[8];
  float mx = -INFINITY;
  for (int k = 0; k < 8; ++k) { v[k] = row[l + 64 * k]; mx = fmaxf(mx, v[k]); }
  mx = wave_max(mx);
  float sm = 0.f;
  for (int k = 0; k < 8; ++k) sm += __expf(v[k] - mx);
  sm = wave_sum(sm);
  const float lse = mx + __logf(sm);
  const int c = i >> 7, g4s = (i >> 5) & 3, e = i & 31;
  for (int k = 0; k < 8; ++k) {
    const int j = l + 64 * k;
    const int jt = j >> 4, jc = j & 15;
    Afrag8[((size_t)(jt * 4 + c) * 64 + g4s * 16 + jc) * 32 + e] = f2fp8_sw(__expf(v[k] - lse));
  }
}

// P LDS: row m (chain), k (state): byte  m*512 + (((k>>4) ^ m)&31)*16 + (k&15)
__device__ __forceinline__ int pswz(int m, int g) { return m * 512 + (((g ^ m) & 31) << 4); }

// ---- main: D = Aexp (A-op, rows j) x P (B-op, cols m=chain) ----
__global__ __launch_bounds__(512, 2)
void hmm_main(const int* __restrict__ obs, const float* __restrict__ lpi,
              const unsigned short* __restrict__ Bexp16,
              const unsigned char* __restrict__ Afrag8, float* __restrict__ parts)
{
  __shared__ __align__(16) unsigned char Pb[CH * S];   // 8 KB fp8
  __shared__ int   obs_s[CH][TT];                      // 32 KB
  __shared__ __align__(16) float pred[CH][NWAVE];

  const int tid = threadIdx.x;
  const int w   = tid >> 6;
  const int l   = tid & 63;
  const int g4  = l >> 4;
  const int mm  = l & 15;          // this thread's chain
  const int grp = blockIdx.x;

  // persistent Aexp fragments: 4 tiles x 4 chunks x 8 VGPR = 128 regs
  i32x8 a_frags[NJT][4];
  #pragma unroll
  for (int ji = 0; ji < NJT; ++ji) {
    const int jt = w + NWAVE * ji;
    #pragma unroll
    for (int c = 0; c < 4; ++c)
      a_frags[ji][c] = *reinterpret_cast<const i32x8*>(
          Afrag8 + ((size_t)(jt * 4 + c) * 64 + l) * 32);
  }

  for (int m = 0; m < CH; ++m)
    obs_s[m][tid] = obs[(size_t)(grp * CH + m) * TT + tid];
  __syncthreads();

  float lsc = 0.f;   // running log-scale for chain mm (replicated across g4)

  for (int t = 0; t < TT; ++t) {
    const bool fin = (t == TT - 1);
    f32x4 vals[NJT];   // rows j = jt*16 + g4*4 + r, col = chain mm

    if (t == 0) {
      const int o0 = obs_s[mm][0];
      #pragma unroll
      for (int ji = 0; ji < NJT; ++ji) {
        const int j0 = (w + NWAVE * ji) * 16 + g4 * 4;
        const f32x4 lp = *reinterpret_cast<const f32x4*>(lpi + j0);
        const u32x2 e = *reinterpret_cast<const u32x2*>(Bexp16 + (size_t)o0 * S + j0);
        vals[ji][0] = lp[0] + __logf(bflo(e[0]));
        vals[ji][1] = lp[1] + __logf(bfhi(e[0]));
        vals[ji][2] = lp[2] + __logf(bflo(e[1]));
        vals[ji][3] = lp[3] + __logf(bfhi(e[1]));
      }
    } else {
      // emission loads for this step (consumed after the MFMA chain -> latency hidden)
      const int ob = obs_s[mm][t];
      u32x2 eb[NJT];
      const unsigned short* bp = Bexp16 + (size_t)ob * S + g4 * 4;
      #pragma unroll
      for (int ji = 0; ji < NJT; ++ji)
        eb[ji] = *reinterpret_cast<const u32x2*>(bp + (w + NWAVE * ji) * 16);

      // P fragments (B-operand): col = mm, k = c*128 + g4*32 + e
      i32x8 af[4];
      #pragma unroll
      for (int c = 0; c < 4; ++c) {
        const int g0 = c * 8 + g4 * 2;
        i32x4 lo = *reinterpret_cast<const i32x4*>(&Pb[pswz(mm, g0)]);
        i32x4 hi = *reinterpret_cast<const i32x4*>(&Pb[pswz(mm, g0 + 1)]);
        af[c] = i32x8{lo[0], lo[1], lo[2], lo[3], hi[0], hi[1], hi[2], hi[3]};
      }
      #pragma unroll
      for (int ji = 0; ji < NJT; ++ji) {
        f32x4 acc = {0.f, 0.f, 0.f, 0.f};
        #pragma unroll
        for (int c = 0; c < 4; ++c) {
#if __has_builtin(__builtin_amdgcn_mfma_scale_f32_16x16x128_f8f6f4)
          acc = __builtin_amdgcn_mfma_scale_f32_16x16x128_f8f6f4(
                    a_frags[ji][c], af[c], acc, 0, 0,
                    0, 0x7f7f7f7f, 0, 0x7f7f7f7f);
#else
          const i64* pa = reinterpret_cast<const i64*>(&a_frags[ji][c]);
          const i64* pb = reinterpret_cast<const i64*>(&af[c]);
          #pragma unroll
          for (int q = 0; q < 4; ++q)
            acc = __builtin_amdgcn_mfma_f32_16x16x32_fp8_fp8(pa[q], pb[q], acc, 0, 0, 0);
#endif
        }
        acc[0] *= bflo(eb[ji][0]);
        acc[1] *= bfhi(eb[ji][0]);
        acc[2] *= bflo(eb[ji][1]);
        acc[3] *= bfhi(eb[ji][1]);
        vals[ji] = acc;
      }
    }

    // reduce this lane's 16 values, then across the 4 lanes sharing chain mm
    float v;
    if (fin) {
      f32x4 sv = vals[0] + vals[1] + vals[2] + vals[3];
      v = (sv[0] + sv[1]) + (sv[2] + sv[3]);
      v += __shfl_xor(v, 16);
      v += __shfl_xor(v, 32);
    } else {
      f32x4 mv;
      #pragma unroll
      for (int r = 0; r < 4; ++r)
        mv[r] = fmaxf(fmaxf(vals[0][r], vals[1][r]), fmaxf(vals[2][r], vals[3][r]));
      v = fmaxf(fmaxf(mv[0], mv[1]), fmaxf(mv[2], mv[3]));
      v = fmaxf(v, __shfl_xor(v, 16));
      v = fmaxf(v, __shfl_xor(v, 32));
    }
    if (g4 == 0) pred[mm][w] = v;
    __syncthreads();

    if (!fin) {
      // per-chain scale from the 8 wave partials (replicated per thread)
      const f32x4 p0 = *reinterpret_cast<const f32x4*>(&pred[mm][0]);
      const f32x4 p1 = *reinterpret_cast<const f32x4*>(&pred[mm][4]);
      const float s = fmaxf(fmaxf(fmaxf(p0[0], p0[1]), fmaxf(p0[2], p0[3])),
                            fmaxf(fmaxf(p1[0], p1[1]), fmaxf(p1[2], p1[3])));
      float inv;
      if (t == 0) { lsc = s;           inv = s; }
      else        { lsc += __logf(s);  inv = __builtin_amdgcn_rcpf(s); }

      // normalized P write: 4 consecutive fp8 bytes per tile -> 1 dword
      #pragma unroll
      for (int ji = 0; ji < NJT; ++ji) {
        const int jt = w + NWAVE * ji;
        float q0, q1, q2, q3;
        if (t == 0) {
          q0 = __expf(vals[ji][0] - inv); q1 = __expf(vals[ji][1] - inv);
          q2 = __expf(vals[ji][2] - inv); q3 = __expf(vals[ji][3] - inv);
        } else {
          q0 = vals[ji][0] * inv; q1 = vals[ji][1] * inv;
          q2 = vals[ji][2] * inv; q3 = vals[ji][3] * inv;
        }
        *reinterpret_cast<unsigned*>(&Pb[pswz(mm, jt) + g4 * 4]) = pack4_fp8(q0, q1, q2, q3);
      }
      __syncthreads();
    } else {
      // final: sum partials, one value per chain, reduce 16 chains in-wave
      if (w == 0 && g4 == 0) {
        const f32x4 p0 = *reinterpret_cast<const f32x4*>(&pred[mm][0]);
        const f32x4 p1 = *reinterpret_cast<const f32x4*>(&pred[mm][4]);
        const float s8 = ((p0[0] + p0[1]) + (p0[2] + p0[3])) +
                         ((p1[0] + p1[1]) + (p1[2] + p1[3]));
        float cl = lsc + __logf(s8);
        for (int d = 1; d < 16; d <<= 1) cl += __shfl_xor(cl, d);
        if (l == 0) parts[grp] = cl;
      }
    }
  }
}

__global__ void final_sum(const float* __restrict__ parts, float* __restrict__ out) {
  out[0] = parts[0] + parts[1] + parts[2] + parts[3];
}

extern "C" void kernel_launch(void* const* d_in, const int* in_sizes, int n_in,
                              void* d_out, int out_size, void* d_ws, size_t ws_size,
                              hipStream_t stream) {
  const int*   obs  = (const int*)d_in[0];
  const float* lgpi = (const float*)d_in[1];
  const float* lgA  = (const float*)d_in[2];
  const float* lgB  = (const float*)d_in[3];
  float* out = (float*)d_out;

  char* ws = (char*)d_ws;
  unsigned short* Bexp16 = (unsigned short*)ws;                          // 1 MB
  unsigned char*  Afrag8 = (unsigned char*)(ws + (size_t)NOBS * S * 2);  // 256 KB
  float*          lpi    = (float*)(ws + (size_t)NOBS * S * 2 + (size_t)S * S);
  float*          parts  = lpi + S;

  prep_pi<<<1, 64, 0, stream>>>(lgpi, lpi);
  prep_B<<<S, 64, 0, stream>>>(lgB, Bexp16);
  prep_A<<<S, 64, 0, stream>>>(lgA, Afrag8);
  hmm_main<<<NGRP, 512, 0, stream>>>(obs, lpi, Bexp16, Afrag8, parts);
  final_sum<<<1, 1, 0, stream>>>(parts, out);
}

// Round 5
// 716.130 us; speedup vs baseline: 5.0542x; 1.1752x over previous
//
#include <hip/hip_runtime.h>

#define S     512
#define NOBS  1024
#define TT    512
#define CH    16     // chains per workgroup (= MFMA N)
#define NWAVE 8
#define NJT   4      // j-tiles (16 rows) per wave
#define NGRP  4

typedef __attribute__((ext_vector_type(4))) float f32x4;
typedef __attribute__((ext_vector_type(4))) int   i32x4;
typedef __attribute__((ext_vector_type(8))) int   i32x8;
typedef __attribute__((ext_vector_type(2))) unsigned int u32x2;
typedef long i64;

__device__ __forceinline__ unsigned short f2bf(float x) {
  unsigned u = __builtin_bit_cast(unsigned, x);
  return (unsigned short)((u + 0x7fffu + ((u >> 16) & 1u)) >> 16);  // RNE
}
__device__ __forceinline__ float bflo(unsigned u) {
  return __builtin_bit_cast(float, u << 16);
}
__device__ __forceinline__ float bfhi(unsigned u) {
  return __builtin_bit_cast(float, u & 0xffff0000u);
}

__device__ __forceinline__ unsigned char f2fp8_sw(float x) {
  x = fminf(fmaxf(x, 0.f), 448.f);
  unsigned u = __builtin_bit_cast(unsigned, x);
  int ex = (int)((u >> 23) & 0xff);
  if (ex >= 121) {
    unsigned m = (u & 0x7fffff) | 0x800000;
    unsigned keep = m >> 20, rest = m & 0xfffff;
    keep += (rest > 0x80000u) || (rest == 0x80000u && (keep & 1));
    int e8 = ex - 127 + 7;
    if (keep == 16) { keep = 8; e8++; }
    if (e8 >= 16) return 0x7e;
    return (unsigned char)((e8 << 3) | (keep & 7));
  } else {
    int m = (int)(x * 512.0f + 0.5f);
    if (m > 8) m = 8;
    return (unsigned char)m;
  }
}

__device__ __forceinline__ unsigned pack4_fp8(float p0, float p1, float p2, float p3) {
#if __has_builtin(__builtin_amdgcn_cvt_pk_fp8_f32)
  int v = __builtin_amdgcn_cvt_pk_fp8_f32(p0, p1, 0, false);
  v = __builtin_amdgcn_cvt_pk_fp8_f32(p2, p3, v, true);
  return (unsigned)v;
#else
  return (unsigned)f2fp8_sw(p0) | ((unsigned)f2fp8_sw(p1) << 8) |
         ((unsigned)f2fp8_sw(p2) << 16) | ((unsigned)f2fp8_sw(p3) << 24);
#endif
}

__device__ __forceinline__ float wave_max(float v) {
  for (int d = 32; d; d >>= 1) v = fmaxf(v, __shfl_xor(v, d));
  return v;
}
__device__ __forceinline__ float wave_sum(float v) {
  for (int d = 32; d; d >>= 1) v += __shfl_xor(v, d);
  return v;
}

// ---- log_pi log-softmax ----
__global__ void prep_pi(const float* __restrict__ log_pi, float* __restrict__ lpi) {
  const int l = threadIdx.x;
  float v[8];
  float mx = -INFINITY;
  for (int k = 0; k < 8; ++k) { v[k] = log_pi[l + 64 * k]; mx = fmaxf(mx, v[k]); }
  mx = wave_max(mx);
  float sm = 0.f;
  for (int k = 0; k < 8; ++k) sm += __expf(v[k] - mx);
  sm = wave_sum(sm);
  const float lse = mx + __logf(sm);
  for (int k = 0; k < 8; ++k) lpi[l + 64 * k] = v[k] - lse;
}

// ---- log_B row log-softmax -> bf16 transposed: Bexp16[o*S + j] ----
__global__ void prep_B(const float* __restrict__ log_B, unsigned short* __restrict__ Bexp16) {
  const int j = blockIdx.x, l = threadIdx.x;
  const float* row = log_B + (size_t)j * NOBS;
  float v[16];
  float mx = -INFINITY;
  for (int k = 0; k < 16; ++k) { v[k] = row[l + 64 * k]; mx = fmaxf(mx, v[k]); }
  mx = wave_max(mx);
  float sm = 0.f;
  for (int k = 0; k < 16; ++k) sm += __expf(v[k] - mx);
  sm = wave_sum(sm);
  const float lse = mx + __logf(sm);
  for (int k = 0; k < 16; ++k) Bexp16[(size_t)(l + 64 * k) * S + j] = f2bf(__expf(v[k] - lse));
}

// ---- log_A row log-softmax -> fp8 e4m3, K=128-chunk fragment order ----
__global__ void prep_A(const float* __restrict__ log_A, unsigned char* __restrict__ Afrag8) {
  const int i = blockIdx.x, l = threadIdx.x;
  const float* row = log_A + (size_t)i * S;
  float v[8];
  float mx = -INFINITY;
  for (int k = 0; k < 8; ++k) { v[k] = row[l + 64 * k]; mx = fmaxf(mx, v[k]); }
  mx = wave_max(mx);
  float sm = 0.f;
  for (int k = 0; k < 8; ++k) sm += __expf(v[k] - mx);
  sm = wave_sum(sm);
  const float lse = mx + __logf(sm);
  const int c = i >> 7, g4s = (i >> 5) & 3, e = i & 31;
  for (int k = 0; k < 8; ++k) {
    const int j = l + 64 * k;
    const int jt = j >> 4, jc = j & 15;
    Afrag8[((size_t)(jt * 4 + c) * 64 + g4s * 16 + jc) * 32 + e] = f2fp8_sw(__expf(v[k] - lse));
  }
}

// P LDS swizzle (within one 8 KB buffer)
__device__ __forceinline__ int pswz(int m, int g) { return m * 512 + (((g ^ m) & 31) << 4); }

__device__ __forceinline__ float max8(const float* p) {
  const f32x4 p0 = *reinterpret_cast<const f32x4*>(p);
  const f32x4 p1 = *reinterpret_cast<const f32x4*>(p + 4);
  return fmaxf(fmaxf(fmaxf(p0[0], p0[1]), fmaxf(p0[2], p0[3])),
               fmaxf(fmaxf(p1[0], p1[1]), fmaxf(p1[2], p1[3])));
}
__device__ __forceinline__ float sum8(const float* p) {
  const f32x4 p0 = *reinterpret_cast<const f32x4*>(p);
  const f32x4 p1 = *reinterpret_cast<const f32x4*>(p + 4);
  return ((p0[0] + p0[1]) + (p0[2] + p0[3])) + ((p1[0] + p1[1]) + (p1[2] + p1[3]));
}

#define CLAMP_LN8 2.0794415f

// ---- main: one barrier per step, predicted scale, double-buffered P/pred ----
__global__ __launch_bounds__(512, 2)
void hmm_main(const int* __restrict__ obs, const float* __restrict__ lpi,
              const unsigned short* __restrict__ Bexp16,
              const unsigned char* __restrict__ Afrag8, float* __restrict__ parts)
{
  __shared__ __align__(16) unsigned char Pb[2][CH * S];   // 16 KB fp8, double-buffered
  __shared__ int obs_s[CH][TT + 1];                        // padded: kills 16-way bank conflict
  __shared__ __align__(16) float pred[2][CH][12];          // stride-12 padding

  const int tid = threadIdx.x;
  const int w = tid >> 6, l = tid & 63, g4 = l >> 4, mm = l & 15;
  const int grp = blockIdx.x;

  // persistent Aexp fragments (AGPR-parked by compiler): 128 regs
  i32x8 a_frags[NJT][4];
  #pragma unroll
  for (int ji = 0; ji < NJT; ++ji) {
    const int jt = w + NWAVE * ji;
    #pragma unroll
    for (int c = 0; c < 4; ++c)
      a_frags[ji][c] = *reinterpret_cast<const i32x8*>(
          Afrag8 + ((size_t)(jt * 4 + c) * 64 + l) * 32);
  }

  for (int m = 0; m < CH; ++m)
    obs_s[m][tid] = obs[(size_t)(grp * CH + m) * TT + tid];
  __syncthreads();

  float lsc, Lu1, e1;   // running log-scale, log u_{t-1}, e_{t-2}

  // ---------------- t = 0 (log domain, exact) ----------------
  {
    const int o0 = obs_s[mm][0];
    f32x4 vals[NJT];
    #pragma unroll
    for (int ji = 0; ji < NJT; ++ji) {
      const int j0 = (w + NWAVE * ji) * 16 + g4 * 4;
      const f32x4 lp = *reinterpret_cast<const f32x4*>(lpi + j0);
      const u32x2 e = *reinterpret_cast<const u32x2*>(Bexp16 + (size_t)o0 * S + j0);
      vals[ji][0] = lp[0] + __logf(bflo(e[0]));
      vals[ji][1] = lp[1] + __logf(bfhi(e[0]));
      vals[ji][2] = lp[2] + __logf(bflo(e[1]));
      vals[ji][3] = lp[3] + __logf(bfhi(e[1]));
    }
    float v = -INFINITY;
    #pragma unroll
    for (int ji = 0; ji < NJT; ++ji)
      v = fmaxf(v, fmaxf(fmaxf(vals[ji][0], vals[ji][1]), fmaxf(vals[ji][2], vals[ji][3])));
    v = fmaxf(v, __shfl_xor(v, 16));
    v = fmaxf(v, __shfl_xor(v, 32));
    if (g4 == 0) pred[0][mm][w] = v;
    __syncthreads();
    const float M0 = max8(&pred[0][mm][0]);
    #pragma unroll
    for (int ji = 0; ji < NJT; ++ji) {
      const int jt = w + NWAVE * ji;
      *reinterpret_cast<unsigned*>(&Pb[0][pswz(mm, jt) + g4 * 4]) =
          pack4_fp8(__expf(vals[ji][0] - M0), __expf(vals[ji][1] - M0),
                    __expf(vals[ji][2] - M0), __expf(vals[ji][3] - M0));
    }
    lsc = M0;
    __syncthreads();
  }

  // ---------------- t = 1 (linear, exact) ----------------
  {
    const int o1 = obs_s[mm][1];
    u32x2 eb[NJT];
    const unsigned short* bp = Bexp16 + (size_t)o1 * S + g4 * 4;
    #pragma unroll
    for (int ji = 0; ji < NJT; ++ji)
      eb[ji] = *reinterpret_cast<const u32x2*>(bp + (w + NWAVE * ji) * 16);
    i32x8 af[4];
    #pragma unroll
    for (int c = 0; c < 4; ++c) {
      const int g0 = c * 8 + g4 * 2;
      i32x4 lo = *reinterpret_cast<const i32x4*>(&Pb[0][pswz(mm, g0)]);
      i32x4 hi = *reinterpret_cast<const i32x4*>(&Pb[0][pswz(mm, g0 + 1)]);
      af[c] = i32x8{lo[0], lo[1], lo[2], lo[3], hi[0], hi[1], hi[2], hi[3]};
    }
    f32x4 vals[NJT];
    #pragma unroll
    for (int ji = 0; ji < NJT; ++ji) {
      f32x4 acc = {0.f, 0.f, 0.f, 0.f};
      #pragma unroll
      for (int c = 0; c < 4; ++c) {
#if __has_builtin(__builtin_amdgcn_mfma_scale_f32_16x16x128_f8f6f4)
        acc = __builtin_amdgcn_mfma_scale_f32_16x16x128_f8f6f4(
                  a_frags[ji][c], af[c], acc, 0, 0, 0, 0x7f7f7f7f, 0, 0x7f7f7f7f);
#else
        const i64* pa = reinterpret_cast<const i64*>(&a_frags[ji][c]);
        const i64* pb = reinterpret_cast<const i64*>(&af[c]);
        #pragma unroll
        for (int q = 0; q < 4; ++q)
          acc = __builtin_amdgcn_mfma_f32_16x16x32_fp8_fp8(pa[q], pb[q], acc, 0, 0, 0);
#endif
      }
      acc[0] *= bflo(eb[ji][0]); acc[1] *= bfhi(eb[ji][0]);
      acc[2] *= bflo(eb[ji][1]); acc[3] *= bfhi(eb[ji][1]);
      vals[ji] = acc;
    }
    float v = -INFINITY;
    #pragma unroll
    for (int ji = 0; ji < NJT; ++ji)
      v = fmaxf(v, fmaxf(fmaxf(vals[ji][0], vals[ji][1]), fmaxf(vals[ji][2], vals[ji][3])));
    v = fmaxf(v, __shfl_xor(v, 16));
    v = fmaxf(v, __shfl_xor(v, 32));
    if (g4 == 0) pred[1][mm][w] = v;
    __syncthreads();
    const float v1 = max8(&pred[1][mm][0]);
    const float inv = __builtin_amdgcn_rcpf(v1);
    Lu1 = __logf(v1); lsc += Lu1; e1 = 0.f;
    #pragma unroll
    for (int ji = 0; ji < NJT; ++ji) {
      const int jt = w + NWAVE * ji;
      *reinterpret_cast<unsigned*>(&Pb[1][pswz(mm, jt) + g4 * 4]) =
          pack4_fp8(vals[ji][0] * inv, vals[ji][1] * inv,
                    vals[ji][2] * inv, vals[ji][3] * inv);
    }
    __syncthreads();
  }

  // ---------------- steady: t = 2 .. 510, ONE barrier per step ----------------
  for (int t = 2; t < TT - 1; ++t) {
    const int cur = t & 1, prv = cur ^ 1;
    const int ob = obs_s[mm][t];

    // last step's written-P max (cross-wave) — ready since last barrier
    const float pm = max8(&pred[prv][mm][0]);
    float e_new = (t == 2) ? 0.f : __logf(pm);

    // emission loads (global; consumed post-MFMA)
    u32x2 eb[NJT];
    const unsigned short* bp = Bexp16 + (size_t)ob * S + g4 * 4;
    #pragma unroll
    for (int ji = 0; ji < NJT; ++ji)
      eb[ji] = *reinterpret_cast<const u32x2*>(bp + (w + NWAVE * ji) * 16);

    // P fragments (B-operand)
    i32x8 af[4];
    #pragma unroll
    for (int c = 0; c < 4; ++c) {
      const int g0 = c * 8 + g4 * 2;
      i32x4 lo = *reinterpret_cast<const i32x4*>(&Pb[prv][pswz(mm, g0)]);
      i32x4 hi = *reinterpret_cast<const i32x4*>(&Pb[prv][pswz(mm, g0 + 1)]);
      af[c] = i32x8{lo[0], lo[1], lo[2], lo[3], hi[0], hi[1], hi[2], hi[3]};
    }

    // predicted scale: log u_t = Lu1 + e_{t-1} + clamp(e_{t-1} - e_{t-2})
    const float dr = fminf(fmaxf(e_new - e1, -CLAMP_LN8), CLAMP_LN8);
    const float Lu = Lu1 + e_new + dr;
    const float inv = __expf(-Lu);
    lsc += Lu; e1 = e_new; Lu1 = Lu;

    float vmax = 0.f;
    #pragma unroll
    for (int ji = 0; ji < NJT; ++ji) {
      f32x4 acc = {0.f, 0.f, 0.f, 0.f};
      #pragma unroll
      for (int c = 0; c < 4; ++c) {
#if __has_builtin(__builtin_amdgcn_mfma_scale_f32_16x16x128_f8f6f4)
        acc = __builtin_amdgcn_mfma_scale_f32_16x16x128_f8f6f4(
                  a_frags[ji][c], af[c], acc, 0, 0, 0, 0x7f7f7f7f, 0, 0x7f7f7f7f);
#else
        const i64* pa = reinterpret_cast<const i64*>(&a_frags[ji][c]);
        const i64* pb = reinterpret_cast<const i64*>(&af[c]);
        #pragma unroll
        for (int q = 0; q < 4; ++q)
          acc = __builtin_amdgcn_mfma_f32_16x16x32_fp8_fp8(pa[q], pb[q], acc, 0, 0, 0);
#endif
      }
      const float q0 = acc[0] * bflo(eb[ji][0]) * inv;
      const float q1 = acc[1] * bfhi(eb[ji][0]) * inv;
      const float q2 = acc[2] * bflo(eb[ji][1]) * inv;
      const float q3 = acc[3] * bfhi(eb[ji][1]) * inv;
      const int jt = w + NWAVE * ji;
      *reinterpret_cast<unsigned*>(&Pb[cur][pswz(mm, jt) + g4 * 4]) =
          pack4_fp8(q0, q1, q2, q3);
      vmax = fmaxf(vmax, fmaxf(fmaxf(q0, q1), fmaxf(q2, q3)));
    }
    // cross-lane max of written P (overlaps other waves' writes)
    vmax = fmaxf(vmax, __shfl_xor(vmax, 16));
    vmax = fmaxf(vmax, __shfl_xor(vmax, 32));
    if (g4 == 0) pred[cur][mm][w] = vmax;
    __syncthreads();
  }

  // ---------------- t = 511 (final: sum) ----------------
  {
    const int t = TT - 1, cur = t & 1, prv = cur ^ 1;   // cur=1, prv=0
    const int ob = obs_s[mm][t];
    const float pm = max8(&pred[prv][mm][0]);
    const float e_new = __logf(pm);
    u32x2 eb[NJT];
    const unsigned short* bp = Bexp16 + (size_t)ob * S + g4 * 4;
    #pragma unroll
    for (int ji = 0; ji < NJT; ++ji)
      eb[ji] = *reinterpret_cast<const u32x2*>(bp + (w + NWAVE * ji) * 16);
    i32x8 af[4];
    #pragma unroll
    for (int c = 0; c < 4; ++c) {
      const int g0 = c * 8 + g4 * 2;
      i32x4 lo = *reinterpret_cast<const i32x4*>(&Pb[prv][pswz(mm, g0)]);
      i32x4 hi = *reinterpret_cast<const i32x4*>(&Pb[prv][pswz(mm, g0 + 1)]);
      af[c] = i32x8{lo[0], lo[1], lo[2], lo[3], hi[0], hi[1], hi[2], hi[3]};
    }
    const float dr = fminf(fmaxf(e_new - e1, -CLAMP_LN8), CLAMP_LN8);
    const float Lu = Lu1 + e_new + dr;
    const float inv = __expf(-Lu);
    lsc += Lu;
    float ssum = 0.f;
    #pragma unroll
    for (int ji = 0; ji < NJT; ++ji) {
      f32x4 acc = {0.f, 0.f, 0.f, 0.f};
      #pragma unroll
      for (int c = 0; c < 4; ++c) {
#if __has_builtin(__builtin_amdgcn_mfma_scale_f32_16x16x128_f8f6f4)
        acc = __builtin_amdgcn_mfma_scale_f32_16x16x128_f8f6f4(
                  a_frags[ji][c], af[c], acc, 0, 0, 0, 0x7f7f7f7f, 0, 0x7f7f7f7f);
#else
        const i64* pa = reinterpret_cast<const i64*>(&a_frags[ji][c]);
        const i64* pb = reinterpret_cast<const i64*>(&af[c]);
        #pragma unroll
        for (int q = 0; q < 4; ++q)
          acc = __builtin_amdgcn_mfma_f32_16x16x32_fp8_fp8(pa[q], pb[q], acc, 0, 0, 0);
#endif
      }
      ssum += acc[0] * bflo(eb[ji][0]) + acc[1] * bfhi(eb[ji][0]) +
              acc[2] * bflo(eb[ji][1]) + acc[3] * bfhi(eb[ji][1]);
    }
    ssum *= inv;
    ssum += __shfl_xor(ssum, 16);
    ssum += __shfl_xor(ssum, 32);
    if (g4 == 0) pred[cur][mm][w] = ssum;
    __syncthreads();
    if (w == 0 && g4 == 0) {
      const float s8 = sum8(&pred[1][mm][0]);
      float cl = lsc + __logf(s8);
      for (int d = 1; d < 16; d <<= 1) cl += __shfl_xor(cl, d);
      if (l == 0) parts[grp] = cl;
    }
  }
}

__global__ void final_sum(const float* __restrict__ parts, float* __restrict__ out) {
  out[0] = parts[0] + parts[1] + parts[2] + parts[3];
}

extern "C" void kernel_launch(void* const* d_in, const int* in_sizes, int n_in,
                              void* d_out, int out_size, void* d_ws, size_t ws_size,
                              hipStream_t stream) {
  const int*   obs  = (const int*)d_in[0];
  const float* lgpi = (const float*)d_in[1];
  const float* lgA  = (const float*)d_in[2];
  const float* lgB  = (const float*)d_in[3];
  float* out = (float*)d_out;

  char* ws = (char*)d_ws;
  unsigned short* Bexp16 = (unsigned short*)ws;                          // 1 MB
  unsigned char*  Afrag8 = (unsigned char*)(ws + (size_t)NOBS * S * 2);  // 256 KB
  float*          lpi    = (float*)(ws + (size_t)NOBS * S * 2 + (size_t)S * S);
  float*          parts  = lpi + S;

  prep_pi<<<1, 64, 0, stream>>>(lgpi, lpi);
  prep_B<<<S, 64, 0, stream>>>(lgB, Bexp16);
  prep_A<<<S, 64, 0, stream>>>(lgA, Afrag8);
  hmm_main<<<NGRP, 512, 0, stream>>>(obs, lpi, Bexp16, Afrag8, parts);
  final_sum<<<1, 1, 0, stream>>>(parts, out);
}